// Round 11
// baseline (310.189 us; speedup 1.0000x reference)
//
#include <hip/hip_runtime.h>
#include <math.h>

// ---------------- problem constants ----------------
constexpr int BATCH = 4;
constexpr int IMG_H = 512, IMG_W = 512;
constexpr int IMG_HW = IMG_H * IMG_W;          // 262144
constexpr int PSTR = BATCH * IMG_HW;           // p-plane stride 1048576

// ---------------- workspace layout (floats) ----------------
constexpr size_t O_PA   = 0;                       // p ping [2][4][512][512] (also split-K partial arena)
constexpr size_t O_PB   = O_PA + 2 * (size_t)PSTR; // p pong
constexpr size_t O_DEN  = O_PB + 2 * (size_t)PSTR; // denoised [4][512][512]
constexpr size_t O_A1   = O_DEN + (size_t)PSTR;    // arena1 (8388608 floats; also head-partial arena)
constexpr size_t O_A2   = O_A1 + 8388608;          // arena2 (2097152 floats)
constexpr size_t O_WT1  = O_A2 + 2097152;          // wT pw1  [32][64]
constexpr size_t O_WT2  = O_WT1 + 32 * 64;
constexpr size_t O_WT3  = O_WT2 + 64 * 128;
constexpr size_t O_WT4  = O_WT3 + 128 * 256;
constexpr size_t O_WTH  = O_WT4 + 256 * 512;
constexpr size_t O_WCOMB= O_WTH + 512 * 1280;      // [1280]
constexpr size_t O_BCOMB= O_WCOMB + 1280;          // [1]
constexpr size_t O_S    = O_BCOMB + 4;             // s field [4][16][16]
constexpr size_t WS_FLOATS = O_S + 1024;

__device__ __forceinline__ float silu_f(float x) {
    return x / (1.0f + expf(-x));
}
__device__ __forceinline__ int clampi(int v, int lo, int hi) {
    return v < lo ? lo : (v > hi ? hi : v);
}

// ---------------- TV Chambolle: register-resident, shuffle-exchange ----------------
// Block = 4 waves. Wave = 64 lanes = 64 columns (cols c0-10 .. c0+53; output
// cols c0..c0+43 are lanes [10,54)). Wave w owns 9 rows (gi = r0-10+9w+k);
// 36 rows cover 16 output rows + 10 halo each side. Grid 1536 blocks (6/CU)
// for issue parallelism (R10's 32-row tile ran at 21% occupancy, 768 blocks).
// img/p0/p1/o live in registers. Horizontal neighbors via __shfl (lane +/-1);
// vertical wave-boundary rows via 2KB LDS (2 barriers/stage). Validity
// shrinks 1 cell/side/iter: after NST=10 iters valid rows/lanes [10,26)/
// [10,54) == exactly the 16x44 output window. Halo garbage is finite and
// never read by valid cells (global-coord guards, skimage rules).
template <int NST, bool FIRST, bool LAST>
__global__ __launch_bounds__(256) void tv_reg(const float* __restrict__ img,
                                              const float* __restrict__ pin,
                                              float* __restrict__ pout) {
    constexpr int ROWS = 9, HL = 10, TC = 44, TR = 16;
    __shared__ float bndP[256], bndO[256];
    const int tid = threadIdx.x;
    const int lane = tid & 63, w = tid >> 6;
    const int b = blockIdx.z;
    const int r0 = blockIdx.y * TR, c0 = blockIdx.x * TC;
    const int gj = c0 - HL + lane;
    const int gjc = clampi(gj, 0, 511);
    const int gib = r0 - HL + w * ROWS;
    const float* I = img + b * IMG_HW;

    float rim[ROWS], rp0[ROWS], rp1[ROWS], ro[ROWS];
#pragma unroll
    for (int k = 0; k < ROWS; ++k) {
        int gi = clampi(gib + k, 0, 511);
        rim[k] = I[(gi << 9) + gjc];
    }
    if (!FIRST) {
        const float* P0 = pin + b * IMG_HW;
        const float* P1 = pin + PSTR + b * IMG_HW;
#pragma unroll
        for (int k = 0; k < ROWS; ++k) {
            int gi = clampi(gib + k, 0, 511);
            rp0[k] = P0[(gi << 9) + gjc];
            rp1[k] = P1[(gi << 9) + gjc];
        }
    }
    const bool gjpos = (gj > 0), gjlt = (gj < 511);

    int s0 = 0;
    if (FIRST) {
        // stage 0 specialized: p == 0  =>  out-field == img
        bndO[tid] = rim[0];
        __syncthreads();
        float odn = (w < 3) ? bndO[tid + 64] : 0.0f;
#pragma unroll
        for (int k = 0; k < ROWS; ++k) {
            float oR = __shfl_down(rim[k], 1);
            float od = (k < ROWS - 1) ? rim[k + 1] : odn;
            int gi = gib + k;
            float gy = (gi < 511) ? od - rim[k] : 0.0f;
            float gx = gjlt ? oR - rim[k] : 0.0f;
            float inv = 1.0f / (1.0f + 2.5f * sqrtf(gy * gy + gx * gx));
            rp0[k] = -0.25f * gy * inv;
            rp1[k] = -0.25f * gx * inv;
        }
        s0 = 1;
    }

    for (int s = s0; s < NST; ++s) {
        __syncthreads();                 // bndO(s-1) readers done before rewrite
        bndP[tid] = rp0[ROWS - 1];
        __syncthreads();
        float pup0 = (w > 0) ? bndP[tid - 64] : 0.0f;
#pragma unroll
        for (int k = 0; k < ROWS; ++k) {
            float p1l = __shfl_up(rp1[k], 1);
            float o = rim[k] - rp0[k] - rp1[k];
            float pup = (k > 0) ? rp0[k - 1] : pup0;
            int gi = gib + k;
            if (gi > 0) o += pup;
            if (gjpos) o += p1l;
            ro[k] = o;
        }
        bndO[tid] = ro[0];
        __syncthreads();
        float odn = (w < 3) ? bndO[tid + 64] : 0.0f;
#pragma unroll
        for (int k = 0; k < ROWS; ++k) {
            float oR = __shfl_down(ro[k], 1);
            float od = (k < ROWS - 1) ? ro[k + 1] : odn;
            int gi = gib + k;
            float gy = (gi < 511) ? od - ro[k] : 0.0f;
            float gx = gjlt ? oR - ro[k] : 0.0f;
            float inv = 1.0f / (1.0f + 2.5f * sqrtf(gy * gy + gx * gx));
            rp0[k] = (rp0[k] - 0.25f * gy) * inv;
            rp1[k] = (rp1[k] - 0.25f * gx) * inv;
        }
    }

    const bool cst = (lane >= HL && lane < HL + TC && gj < 512);
    if (LAST) {
        // den = img + div(p) on output tile
        __syncthreads();
        bndP[tid] = rp0[ROWS - 1];
        __syncthreads();
        float pup0 = (w > 0) ? bndP[tid - 64] : 0.0f;
        float* D = pout + b * IMG_HW;
#pragma unroll
        for (int k = 0; k < ROWS; ++k) {
            float p1l = __shfl_up(rp1[k], 1);
            int gi = gib + k;
            int rk = w * ROWS + k;
            float o = rim[k] - rp0[k] - rp1[k];
            float pup = (k > 0) ? rp0[k - 1] : pup0;
            if (gi > 0) o += pup;
            if (gjpos) o += p1l;
            if (rk >= HL && rk < HL + TR && cst) D[(gi << 9) + gj] = o;
        }
    } else {
        float* Q0 = pout + b * IMG_HW;
        float* Q1 = pout + PSTR + b * IMG_HW;
#pragma unroll
        for (int k = 0; k < ROWS; ++k) {
            int rk = w * ROWS + k;
            int gi = gib + k;
            if (rk >= HL && rk < HL + TR && cst) {
                Q0[(gi << 9) + gj] = rp0[k];
                Q1[(gi << 9) + gj] = rp1[k];
            }
        }
    }
}

// ---------------- fused stem (3x3 s2 + SiLU) + dw1 (3x3 s2 + SiLU) + pw1 (1x1 32->64 + SiLU) ----
__global__ __launch_bounds__(256) void stem_dw1_pw1(const float* __restrict__ den,
                                                    const float* __restrict__ stemw,
                                                    const float* __restrict__ dw1w,
                                                    const float* __restrict__ pw1T,
                                                    float* __restrict__ out) {
    __shared__ float sDen[35 * 36];
    __shared__ float sStem[8 * 323];   // 8 ch x (17 rows x stride 19)
    __shared__ float sDw[32 * 64];     // dw1 out: [ic][px], px = dy*8+dx
    __shared__ float sW[576];
    __shared__ __align__(16) float sWp[2048];  // pw1T [ic][oc]
    const int tid = threadIdx.x;
    const int b = blockIdx.z;
    const int r0 = blockIdx.y * 32, c0 = blockIdx.x * 32;
    const float* D = den + b * IMG_HW;
    for (int e = tid; e < 576; e += 256) sW[e] = (e < 288) ? stemw[e] : dw1w[e - 288];
    for (int e = tid; e < 2048; e += 256) sWp[e] = pw1T[e];
    for (int e = tid; e < 35 * 35; e += 256) {
        int li = e / 35, lj = e % 35;
        int gi = r0 - 3 + li, gjj = c0 - 3 + lj;
        sDen[li * 36 + lj] = (gi >= 0 && gjj >= 0) ? D[(gi << 9) + gjj] : 0.0f;
    }
    __syncthreads();

    for (int g = 0; g < 4; ++g) {
        if (g) __syncthreads();
        // phase A: stem for channels 8g..8g+7 at 17x17 positions
        for (int e = tid; e < 2312; e += 256) {      // 289 pos x 8 ch
            int pos = e >> 3, cl = e & 7;
            int sy = pos / 17, sx = pos % 17;
            int c = 8 * g + cl;
            const float* wc = &sW[c * 9];
            const float* dbase = &sDen[(2 * sy) * 36 + 2 * sx];
            float a = 0.0f;
#pragma unroll
            for (int ky = 0; ky < 3; ++ky)
#pragma unroll
                for (int kx = 0; kx < 3; ++kx)
                    a = fmaf(wc[ky * 3 + kx], dbase[ky * 36 + kx], a);
            sStem[cl * 323 + sy * 19 + sx] = silu_f(a);
        }
        __syncthreads();
        // phase B: dw1 for channels 8g..8g+7 -> sDw
        for (int e = tid; e < 512; e += 256) {
            int cl = e >> 6, dy = (e >> 3) & 7, dx = e & 7;
            int c = 8 * g + cl;
            float acc = 0.0f;
#pragma unroll
            for (int ky = 0; ky < 3; ++ky)
#pragma unroll
                for (int kx = 0; kx < 3; ++kx) {
                    int sgy = (r0 >> 1) - 1 + 2 * dy + ky;
                    int sgx = (c0 >> 1) - 1 + 2 * dx + kx;
                    float v = (sgy >= 0 && sgx >= 0)
                        ? sStem[cl * 323 + (2 * dy + ky) * 19 + 2 * dx + kx] : 0.0f;
                    acc = fmaf(sW[288 + c * 9 + ky * 3 + kx], v, acc);
                }
            sDw[c * 64 + (dy << 3) + dx] = silu_f(acc);
        }
    }
    __syncthreads();

    // phase C: pw1 1x1 GEMM 32->64 + SiLU. px = lane, oc-quad = wave.
    const int px = tid & 63, oc0 = (tid >> 6) * 16;
    float acc[16];
#pragma unroll
    for (int j = 0; j < 16; ++j) acc[j] = 0.0f;
    for (int ic = 0; ic < 32; ++ic) {
        float v = sDw[ic * 64 + px];
        const float* wr = &sWp[ic * 64 + oc0];
#pragma unroll
        for (int q = 0; q < 4; ++q) {
            float4 w4 = *(const float4*)(wr + q * 4);
            acc[q * 4 + 0] = fmaf(v, w4.x, acc[q * 4 + 0]);
            acc[q * 4 + 1] = fmaf(v, w4.y, acc[q * 4 + 1]);
            acc[q * 4 + 2] = fmaf(v, w4.z, acc[q * 4 + 2]);
            acc[q * 4 + 3] = fmaf(v, w4.w, acc[q * 4 + 3]);
        }
    }
    const int gpos = ((r0 >> 2) + (px >> 3)) * 128 + (c0 >> 2) + (px & 7);
    float* ob = out + (size_t)b * 64 * 16384 + (size_t)oc0 * 16384 + gpos;
#pragma unroll
    for (int j = 0; j < 16; ++j) ob[(size_t)j * 16384] = silu_f(acc[j]);
}

// ---------------- depthwise 3x3 s2 pad1 + SiLU ----------------
template <int C, int HIN>
__global__ __launch_bounds__(256) void dw_kernel(const float* __restrict__ in,
                                                 const float* __restrict__ w,
                                                 float* __restrict__ out) {
    constexpr int HO = HIN / 2;
    int t = blockIdx.x * 256 + threadIdx.x;       // B*C*HO*HO
    int x = t % HO;
    int y = (t / HO) % HO;
    int c = (t / (HO * HO)) % C;
    int b = t / (HO * HO * C);
    const float* I = in + ((size_t)(b * C + c)) * (HIN * HIN);
    const float* wc = w + c * 9;
    int iy = 2 * y - 1, ix = 2 * x - 1;
    float acc = 0.0f;
#pragma unroll
    for (int ky = 0; ky < 3; ++ky)
#pragma unroll
        for (int kx = 0; kx < 3; ++kx) {
            int yy = iy + ky, xx = ix + kx;
            float vv = (yy >= 0 && xx >= 0) ? I[yy * HIN + xx] : 0.0f;
            acc = fmaf(wc[ky * 3 + kx], vv, acc);
        }
    out[t] = silu_f(acc);
}

// ---------------- depthwise 3x3 s2 + fused 2-way split-K reduce + SiLU input ----------------
template <int C, int HIN>
__global__ __launch_bounds__(256) void dw_reduce2_kernel(const float* __restrict__ part,
                                                         const float* __restrict__ w,
                                                         float* __restrict__ out) {
    constexpr int HO = HIN / 2;
    int t = blockIdx.x * 256 + threadIdx.x;
    int x = t % HO;
    int y = (t / HO) % HO;
    int c = (t / (HO * HO)) % C;
    int b = t / (HO * HO * C);
    const float* Ia = part + ((size_t)(b * C + c)) * (HIN * HIN);
    const float* Ib = Ia + (size_t)BATCH * C * HIN * HIN;
    const float* wc = w + c * 9;
    int iy = 2 * y - 1, ix = 2 * x - 1;
    float acc = 0.0f;
#pragma unroll
    for (int ky = 0; ky < 3; ++ky)
#pragma unroll
        for (int kx = 0; kx < 3; ++kx) {
            int yy = iy + ky, xx = ix + kx;
            float vv = 0.0f;
            if (yy >= 0 && xx >= 0) {
                int o = yy * HIN + xx;
                vv = silu_f(Ia[o] + Ib[o]);
            }
            acc = fmaf(wc[ky * 3 + kx], vv, acc);
        }
    out[t] = silu_f(acc);
}

// ---------------- pointwise 1x1 conv: double-buffered, split-K GEMM ----------------
template <int ICT, int NSIN, int NSPLIT, int OC, bool SILU>
__global__ __launch_bounds__(256) void pw_gemm(const float* __restrict__ in,
                                               const float* __restrict__ wT,
                                               float* __restrict__ out,
                                               int HW) {
    constexpr int KC = 32, TP = 64, TOC = 64, OPT = 4, PPT = 4;
    constexpr int KS = ICT / NSPLIT;
    constexpr int NC = KS / KC;
    constexpr int NOG = TOC / OPT;                // 16
    constexpr int PV4 = KC * TP / 4 / 256;        // 2 float4/thread (px)
    constexpr int WV4 = KC * TOC / 4 / 256;       // 2 float4/thread (w)
    static_assert(KS % KC == 0, "split");
    __shared__ __align__(16) float sPx[2][KC * TP];
    __shared__ __align__(16) float sW[2][KC * TOC];
    const int tid = threadIdx.x;
    const int zb = blockIdx.z;
    const int b = zb / NSPLIT, ks = zb % NSPLIT;
    const int p0 = blockIdx.x * TP;
    const int oc0 = blockIdx.y * TOC;
    const int ocg = tid % NOG, pxg = tid / NOG;   // pxg in [0,16)
    const size_t instride = (size_t)BATCH * ICT * HW;
    const float* gin0 = in + ((size_t)b * ICT + ks * KS) * HW + p0;
    const float* gw0  = wT + ((size_t)(ks * KS)) * OC + oc0;

    float4 rp[PV4], rw[WV4];
    auto load_chunk = [&](int cc) {
        const float* gin = gin0 + (size_t)cc * KC * HW;
#pragma unroll
        for (int i = 0; i < PV4; ++i) {
            int e = tid + i * 256;
            int row = e / (TP / 4), col = e % (TP / 4);
            const float* base = gin + (size_t)row * HW + col * 4;
            float4 a = *(const float4*)base;
#pragma unroll
            for (int s = 1; s < NSIN; ++s) {
                float4 t4 = *(const float4*)(base + (size_t)s * instride);
                a.x += t4.x; a.y += t4.y; a.z += t4.z; a.w += t4.w;
            }
            if (NSIN > 1) {
                a.x = silu_f(a.x); a.y = silu_f(a.y);
                a.z = silu_f(a.z); a.w = silu_f(a.w);
            }
            rp[i] = a;
        }
        const float* gw = gw0 + (size_t)cc * KC * OC;
#pragma unroll
        for (int i = 0; i < WV4; ++i) {
            int e = tid + i * 256;
            int row = e / (TOC / 4), col = e % (TOC / 4);
            rw[i] = *(const float4*)(gw + (size_t)row * OC + col * 4);
        }
    };
    auto store_chunk = [&](int buf) {
#pragma unroll
        for (int i = 0; i < PV4; ++i) ((float4*)sPx[buf])[tid + i * 256] = rp[i];
#pragma unroll
        for (int i = 0; i < WV4; ++i) ((float4*)sW[buf])[tid + i * 256] = rw[i];
    };

    float acc[OPT][PPT];
#pragma unroll
    for (int o = 0; o < OPT; ++o)
#pragma unroll
        for (int p = 0; p < PPT; ++p) acc[o][p] = 0.0f;

    load_chunk(0);
    store_chunk(0);
    __syncthreads();
    for (int cc = 0; cc < NC; ++cc) {
        if (cc + 1 < NC) load_chunk(cc + 1);
        const int buf = cc & 1;
#pragma unroll 4
        for (int k = 0; k < KC; ++k) {
            float4 pv = *(const float4*)&sPx[buf][k * TP + pxg * PPT];
            float4 wv = *(const float4*)&sW[buf][k * TOC + ocg * OPT];
            float w0 = wv.x, w1 = wv.y, w2 = wv.z, w3 = wv.w;
            acc[0][0] = fmaf(pv.x, w0, acc[0][0]);
            acc[0][1] = fmaf(pv.y, w0, acc[0][1]);
            acc[0][2] = fmaf(pv.z, w0, acc[0][2]);
            acc[0][3] = fmaf(pv.w, w0, acc[0][3]);
            acc[1][0] = fmaf(pv.x, w1, acc[1][0]);
            acc[1][1] = fmaf(pv.y, w1, acc[1][1]);
            acc[1][2] = fmaf(pv.z, w1, acc[1][2]);
            acc[1][3] = fmaf(pv.w, w1, acc[1][3]);
            acc[2][0] = fmaf(pv.x, w2, acc[2][0]);
            acc[2][1] = fmaf(pv.y, w2, acc[2][1]);
            acc[2][2] = fmaf(pv.z, w2, acc[2][2]);
            acc[2][3] = fmaf(pv.w, w2, acc[2][3]);
            acc[3][0] = fmaf(pv.x, w3, acc[3][0]);
            acc[3][1] = fmaf(pv.y, w3, acc[3][1]);
            acc[3][2] = fmaf(pv.z, w3, acc[3][2]);
            acc[3][3] = fmaf(pv.w, w3, acc[3][3]);
        }
        if (cc + 1 < NC) {
            store_chunk((cc + 1) & 1);
            __syncthreads();
        }
    }

    float* ob;
    if (NSPLIT == 1)
        ob = out + ((size_t)(b * OC + oc0 + ocg * OPT)) * HW + p0 + pxg * PPT;
    else
        ob = out + (((size_t)(ks * BATCH + b)) * OC + oc0 + ocg * OPT) * HW + p0 + pxg * PPT;
#pragma unroll
    for (int o = 0; o < OPT; ++o) {
        float4 r;
        r.x = SILU ? silu_f(acc[o][0]) : acc[o][0];
        r.y = SILU ? silu_f(acc[o][1]) : acc[o][1];
        r.z = SILU ? silu_f(acc[o][2]) : acc[o][2];
        r.w = SILU ? silu_f(acc[o][3]) : acc[o][3];
        *(float4*)(ob + (size_t)o * HW) = r;
    }
}

// ---------------- prep: weight transposes + combined tail weights ----------------
__global__ __launch_bounds__(256) void prep_kernel(const float* __restrict__ pw1,
                                                   const float* __restrict__ pw2,
                                                   const float* __restrict__ pw3,
                                                   const float* __restrict__ pw4,
                                                   const float* __restrict__ headw,
                                                   const float* __restrict__ projw,
                                                   const float* __restrict__ projb,
                                                   const float* __restrict__ finalw,
                                                   const float* __restrict__ finalb,
                                                   float* __restrict__ ws) {
    int t = blockIdx.x * 256 + threadIdx.x;
    if (t < 2048) {                                  // pw1: 64x32 -> [32][64]
        int e = t; int ic = e >> 6, oc = e & 63;
        ws[O_WT1 + e] = pw1[oc * 32 + ic];
    } else if (t < 10240) {                          // pw2: 128x64 -> [64][128]
        int e = t - 2048; int ic = e >> 7, oc = e & 127;
        ws[O_WT2 + e] = pw2[oc * 64 + ic];
    } else if (t < 43008) {                          // pw3: 256x128 -> [128][256]
        int e = t - 10240; int ic = e >> 8, oc = e & 255;
        ws[O_WT3 + e] = pw3[oc * 128 + ic];
    } else if (t < 174080) {                         // pw4: 512x256 -> [256][512]
        int e = t - 43008; int ic = e >> 9, oc = e & 511;
        ws[O_WT4 + e] = pw4[oc * 256 + ic];
    } else if (t < 829440) {                         // head: 1280x512 -> [512][1280]
        int e = t - 174080; int ic = e / 1280, oc = e % 1280;
        ws[O_WTH + e] = headw[oc * 512 + ic];
    } else if (t < 830720) {                         // w_comb[k] = sum_ch fw[ch]*proj_w[ch,k]
        int k = t - 829440;
        float a = 0.0f;
        for (int ch = 0; ch < 64; ++ch) a = fmaf(finalw[ch], projw[ch * 1280 + k], a);
        ws[O_WCOMB + k] = a;
    } else if (t == 830720) {                        // b_comb = dot(fw, proj_b)
        float a = 0.0f;
        for (int ch = 0; ch < 64; ++ch) a = fmaf(finalw[ch], projb[ch], a);
        ws[O_BCOMB] = a;
    }
}

// ---------------- fused head-partial reduce (4-way) + SiLU + wcomb dot ----------------
__global__ __launch_bounds__(256) void tail_head(const float* __restrict__ part,
                                                 const float* __restrict__ wcomb,
                                                 const float* __restrict__ bcomb,
                                                 float* __restrict__ s) {
    __shared__ float red[256];
    constexpr size_t PS = (size_t)4 * 1280 * 256;  // per-split stride
    int b = blockIdx.x >> 4;                      // 64 blocks: 4 batch x 16 px-groups
    int px0 = (blockIdx.x & 15) << 4;
    int px = threadIdx.x & 15, kg = threadIdx.x >> 4;   // 16 k-groups of 80
    const float* h0 = part + (size_t)b * 1280 * 256 + px0 + px;
    float acc = 0.0f;
    int k0 = kg * 80;
    for (int k = k0; k < k0 + 80; ++k) {
        size_t off = (size_t)k * 256;
        float v = silu_f(h0[off] + h0[off + PS] + h0[off + 2 * PS] + h0[off + 3 * PS]);
        acc = fmaf(wcomb[k], v, acc);
    }
    red[threadIdx.x] = acc;
    __syncthreads();
    if (threadIdx.x < 16) {
        float a = bcomb[0];
#pragma unroll
        for (int g = 0; g < 16; ++g) a += red[g * 16 + threadIdx.x];
        s[b * 256 + px0 + threadIdx.x] = a;
    }
}

// ---------------- fused bilinear(16->512) + 2-level Haar LL + final bias ----------------
__global__ __launch_bounds__(256) void resize_haar(const float* __restrict__ s,
                                                   const float* __restrict__ finalb,
                                                   float* __restrict__ out) {
    int t = blockIdx.x * 256 + threadIdx.x;       // 4*128*128
    int c = t & 127, r = (t >> 7) & 127, b = t >> 14;
    const float* S = s + b * 256;
    float acc = 0.0f;
#pragma unroll
    for (int j = 0; j < 4; ++j) {
        float sy = ((4 * r + j) + 0.5f) * (1.0f / 32.0f) - 0.5f;
        int y0 = (int)floorf(sy);
        float fy = sy - (float)y0;
        int ya = y0 < 0 ? 0 : y0;
        int yb = (y0 + 1) > 15 ? 15 : (y0 + 1);
#pragma unroll
        for (int i = 0; i < 4; ++i) {
            float sx = ((4 * c + i) + 0.5f) * (1.0f / 32.0f) - 0.5f;
            int x0 = (int)floorf(sx);
            float fx = sx - (float)x0;
            int xa = x0 < 0 ? 0 : x0;
            int xb = (x0 + 1) > 15 ? 15 : (x0 + 1);
            float v0 = S[ya * 16 + xa] * (1.0f - fx) + S[ya * 16 + xb] * fx;
            float v1 = S[yb * 16 + xa] * (1.0f - fx) + S[yb * 16 + xb] * fx;
            acc += v0 * (1.0f - fy) + v1 * fy;
        }
    }
    out[t] = 0.25f * acc + finalb[0];
}

// ---------------- launch ----------------
extern "C" void kernel_launch(void* const* d_in, const int* in_sizes, int n_in,
                              void* d_out, int out_size, void* d_ws, size_t ws_size,
                              hipStream_t stream) {
    if (ws_size < WS_FLOATS * sizeof(float)) return;

    const float* img    = (const float*)d_in[0];
    const float* stem_w = (const float*)d_in[1];
    const float* dw1_w  = (const float*)d_in[2];
    const float* pw1_w  = (const float*)d_in[3];
    const float* dw2_w  = (const float*)d_in[4];
    const float* pw2_w  = (const float*)d_in[5];
    const float* dw3_w  = (const float*)d_in[6];
    const float* pw3_w  = (const float*)d_in[7];
    const float* dw4_w  = (const float*)d_in[8];
    const float* pw4_w  = (const float*)d_in[9];
    const float* head_w = (const float*)d_in[10];
    const float* proj_w = (const float*)d_in[11];
    const float* proj_b = (const float*)d_in[12];
    const float* final_w= (const float*)d_in[13];
    const float* final_b= (const float*)d_in[14];
    float* ws  = (float*)d_ws;
    float* out = (float*)d_out;

    // weight prep
    prep_kernel<<<3246, 256, 0, stream>>>(pw1_w, pw2_w, pw3_w, pw4_w, head_w,
                                          proj_w, proj_b, final_w, final_b, ws);

    // TV Chambolle: 20 iterations in 2 register-resident launches (10+10).
    dim3 tvg(12, 32, 4);                           // 44-col x 16-row output tiles (1536 blocks)
    tv_reg<10, true,  false><<<tvg, 256, 0, stream>>>(img, img,       ws + O_PA);  // 1-10
    tv_reg<10, false, true ><<<tvg, 256, 0, stream>>>(img, ws + O_PA, ws + O_DEN); // 11-20 -> den

    // fused stem + dw1 + pw1 (den -> [B][64][128][128])
    stem_dw1_pw1<<<dim3(16, 16, 4), 256, 0, stream>>>(ws + O_DEN, stem_w, dw1_w,
                                                      ws + O_WT1, ws + O_A1);

    // backbone
    dw_kernel<64, 128><<<4096, 256, 0, stream>>>(ws + O_A1, dw2_w, ws + O_A2);
    pw_gemm<64, 1, 2, 128, false><<<dim3(64, 2, 8), 256, 0, stream>>>(ws + O_A2, ws + O_WT2, ws + O_PA, 4096);

    dw_reduce2_kernel<128, 64><<<2048, 256, 0, stream>>>(ws + O_PA, dw3_w, ws + O_A1);
    pw_gemm<128, 1, 2, 256, false><<<dim3(16, 4, 8), 256, 0, stream>>>(ws + O_A1, ws + O_WT3, ws + O_PA, 1024);

    dw_reduce2_kernel<256, 32><<<1024, 256, 0, stream>>>(ws + O_PA, dw4_w, ws + O_A2);
    pw_gemm<256, 1, 4, 512, false><<<dim3(4, 8, 16), 256, 0, stream>>>(ws + O_A2, ws + O_WT4, ws + O_PA, 256);

    // head 512->1280 @16x16: fused 4-way partial reduce+SiLU at staging, split-4 raw out -> A1
    pw_gemm<512, 4, 4, 1280, false><<<dim3(4, 20, 16), 256, 0, stream>>>(ws + O_PA, ws + O_WTH, ws + O_A1, 256);
    tail_head<<<64, 256, 0, stream>>>(ws + O_A1, ws + O_WCOMB, ws + O_BCOMB, ws + O_S);

    resize_haar<<<256, 256, 0, stream>>>(ws + O_S, final_b, out);
}

// Round 12
// 292.534 us; speedup vs baseline: 1.0604x; 1.0604x over previous
//
#include <hip/hip_runtime.h>
#include <math.h>

// ---------------- problem constants ----------------
constexpr int BATCH = 4;
constexpr int IMG_H = 512, IMG_W = 512;
constexpr int IMG_HW = IMG_H * IMG_W;          // 262144
constexpr int PSTR = BATCH * IMG_HW;           // p-plane stride 1048576

// ---------------- workspace layout (floats) ----------------
constexpr size_t O_PA   = 0;                       // p ping [2][4][512][512] (also split-K partial arena)
constexpr size_t O_PB   = O_PA + 2 * (size_t)PSTR; // p pong
constexpr size_t O_DEN  = O_PB + 2 * (size_t)PSTR; // denoised [4][512][512]
constexpr size_t O_A1   = O_DEN + (size_t)PSTR;    // arena1 (8388608 floats; also head-partial arena)
constexpr size_t O_A2   = O_A1 + 8388608;          // arena2 (2097152 floats)
constexpr size_t O_WT1  = O_A2 + 2097152;          // wT pw1  [32][64]
constexpr size_t O_WT2  = O_WT1 + 32 * 64;
constexpr size_t O_WT3  = O_WT2 + 64 * 128;
constexpr size_t O_WT4  = O_WT3 + 128 * 256;
constexpr size_t O_WTH  = O_WT4 + 256 * 512;
constexpr size_t O_WCOMB= O_WTH + 512 * 1280;      // [1280]
constexpr size_t O_BCOMB= O_WCOMB + 1280;          // [1]
constexpr size_t O_S    = O_BCOMB + 4;             // s field [4][16][16]
constexpr size_t WS_FLOATS = O_S + 1024;

__device__ __forceinline__ float silu_f(float x) {
    return x / (1.0f + expf(-x));
}
__device__ __forceinline__ int clampi(int v, int lo, int hi) {
    return v < lo ? lo : (v > hi ? hi : v);
}

// ---------------- TV Chambolle: register-resident, shuffle-exchange ----------------
// R10 tiling (32-row tiles, ROWS=13, 768 blocks): TV is VALU-WORK bound, not
// occupancy bound (R11's 16-row tile raised occupancy 21->38% but work 1.38x
// -> net regression). New: block-uniform INTERIOR fast path — blocks whose
// compute region rows [r0-10,r0+42) x cols [c0-10,c0+54) lie in [1,510]^2
// (73% of blocks) drop all boundary guards; every computed cell is a true
// interior cell so the guard-free update is identical. Halo-erosion validity
// (1 cell/side/iter; output rows [10,42) lanes [10,54)) is unchanged: w0/k0
// pup0=0 and edge shuffles produce the same garbage-only-in-halo pattern.
template <int NST, bool FIRST, bool LAST>
__global__ __launch_bounds__(256) void tv_reg(const float* __restrict__ img,
                                              const float* __restrict__ pin,
                                              float* __restrict__ pout) {
    constexpr int ROWS = 13, HL = 10, TC = 44, TR = 32;
    __shared__ float bndP[256], bndO[256];
    const int tid = threadIdx.x;
    const int lane = tid & 63, w = tid >> 6;
    const int b = blockIdx.z;
    const int r0 = blockIdx.y * TR, c0 = blockIdx.x * TC;
    const int gj = c0 - HL + lane;
    const int gjc = clampi(gj, 0, 511);
    const int gib = r0 - HL + w * ROWS;
    const float* I = img + b * IMG_HW;
    const bool interior = (r0 - HL >= 1) && (r0 + 4 * ROWS - HL <= 511) &&
                          (c0 - HL >= 1) && (c0 + 64 - HL <= 511);

    float rim[ROWS], rp0[ROWS], rp1[ROWS], ro[ROWS];
#pragma unroll
    for (int k = 0; k < ROWS; ++k) {
        int gi = clampi(gib + k, 0, 511);
        rim[k] = I[(gi << 9) + gjc];
    }
    if (!FIRST) {
        const float* P0 = pin + b * IMG_HW;
        const float* P1 = pin + PSTR + b * IMG_HW;
#pragma unroll
        for (int k = 0; k < ROWS; ++k) {
            int gi = clampi(gib + k, 0, 511);
            rp0[k] = P0[(gi << 9) + gjc];
            rp1[k] = P1[(gi << 9) + gjc];
        }
    }
    const bool gjpos = (gj > 0), gjlt = (gj < 511);

    int s0 = 0;
    if (FIRST) {
        // stage 0 specialized: p == 0  =>  out-field == img
        bndO[tid] = rim[0];
        __syncthreads();
        float odn = (w < 3) ? bndO[tid + 64] : 0.0f;
        if (interior) {
#pragma unroll
            for (int k = 0; k < ROWS; ++k) {
                float oR = __shfl_down(rim[k], 1);
                float od = (k < ROWS - 1) ? rim[k + 1] : odn;
                float gy = od - rim[k];
                float gx = oR - rim[k];
                float inv = 1.0f / (1.0f + 2.5f * sqrtf(gy * gy + gx * gx));
                rp0[k] = -0.25f * gy * inv;
                rp1[k] = -0.25f * gx * inv;
            }
        } else {
#pragma unroll
            for (int k = 0; k < ROWS; ++k) {
                float oR = __shfl_down(rim[k], 1);
                float od = (k < ROWS - 1) ? rim[k + 1] : odn;
                int gi = gib + k;
                float gy = (gi < 511) ? od - rim[k] : 0.0f;
                float gx = gjlt ? oR - rim[k] : 0.0f;
                float inv = 1.0f / (1.0f + 2.5f * sqrtf(gy * gy + gx * gx));
                rp0[k] = -0.25f * gy * inv;
                rp1[k] = -0.25f * gx * inv;
            }
        }
        s0 = 1;
    }

    for (int s = s0; s < NST; ++s) {
        __syncthreads();                 // bndO(s-1) readers done before rewrite
        bndP[tid] = rp0[ROWS - 1];
        __syncthreads();
        float pup0 = (w > 0) ? bndP[tid - 64] : 0.0f;
        if (interior) {
#pragma unroll
            for (int k = 0; k < ROWS; ++k) {
                float p1l = __shfl_up(rp1[k], 1);
                float pup = (k > 0) ? rp0[k - 1] : pup0;
                ro[k] = rim[k] - rp0[k] - rp1[k] + pup + p1l;
            }
            bndO[tid] = ro[0];
            __syncthreads();
            float odn = (w < 3) ? bndO[tid + 64] : 0.0f;
#pragma unroll
            for (int k = 0; k < ROWS; ++k) {
                float oR = __shfl_down(ro[k], 1);
                float od = (k < ROWS - 1) ? ro[k + 1] : odn;
                float gy = od - ro[k];
                float gx = oR - ro[k];
                float inv = 1.0f / (1.0f + 2.5f * sqrtf(gy * gy + gx * gx));
                rp0[k] = (rp0[k] - 0.25f * gy) * inv;
                rp1[k] = (rp1[k] - 0.25f * gx) * inv;
            }
        } else {
#pragma unroll
            for (int k = 0; k < ROWS; ++k) {
                float p1l = __shfl_up(rp1[k], 1);
                float o = rim[k] - rp0[k] - rp1[k];
                float pup = (k > 0) ? rp0[k - 1] : pup0;
                int gi = gib + k;
                if (gi > 0) o += pup;
                if (gjpos) o += p1l;
                ro[k] = o;
            }
            bndO[tid] = ro[0];
            __syncthreads();
            float odn = (w < 3) ? bndO[tid + 64] : 0.0f;
#pragma unroll
            for (int k = 0; k < ROWS; ++k) {
                float oR = __shfl_down(ro[k], 1);
                float od = (k < ROWS - 1) ? ro[k + 1] : odn;
                int gi = gib + k;
                float gy = (gi < 511) ? od - ro[k] : 0.0f;
                float gx = gjlt ? oR - ro[k] : 0.0f;
                float inv = 1.0f / (1.0f + 2.5f * sqrtf(gy * gy + gx * gx));
                rp0[k] = (rp0[k] - 0.25f * gy) * inv;
                rp1[k] = (rp1[k] - 0.25f * gx) * inv;
            }
        }
    }

    const bool cst = (lane >= HL && lane < HL + TC && gj < 512);
    if (LAST) {
        // den = img + div(p) on output tile
        __syncthreads();
        bndP[tid] = rp0[ROWS - 1];
        __syncthreads();
        float pup0 = (w > 0) ? bndP[tid - 64] : 0.0f;
        float* D = pout + b * IMG_HW;
#pragma unroll
        for (int k = 0; k < ROWS; ++k) {
            float p1l = __shfl_up(rp1[k], 1);
            int gi = gib + k;
            int rk = w * ROWS + k;
            float o = rim[k] - rp0[k] - rp1[k];
            float pup = (k > 0) ? rp0[k - 1] : pup0;
            if (gi > 0) o += pup;
            if (gjpos) o += p1l;
            if (rk >= HL && rk < HL + TR && cst) D[(gi << 9) + gj] = o;
        }
    } else {
        float* Q0 = pout + b * IMG_HW;
        float* Q1 = pout + PSTR + b * IMG_HW;
#pragma unroll
        for (int k = 0; k < ROWS; ++k) {
            int rk = w * ROWS + k;
            int gi = gib + k;
            if (rk >= HL && rk < HL + TR && cst) {
                Q0[(gi << 9) + gj] = rp0[k];
                Q1[(gi << 9) + gj] = rp1[k];
            }
        }
    }
}

// ---------------- fused stem (3x3 s2 + SiLU) + dw1 (3x3 s2 + SiLU) + pw1 (1x1 32->64 + SiLU) ----
__global__ __launch_bounds__(256) void stem_dw1_pw1(const float* __restrict__ den,
                                                    const float* __restrict__ stemw,
                                                    const float* __restrict__ dw1w,
                                                    const float* __restrict__ pw1T,
                                                    float* __restrict__ out) {
    __shared__ float sDen[35 * 36];
    __shared__ float sStem[8 * 323];   // 8 ch x (17 rows x stride 19)
    __shared__ float sDw[32 * 64];     // dw1 out: [ic][px], px = dy*8+dx
    __shared__ float sW[576];
    __shared__ __align__(16) float sWp[2048];  // pw1T [ic][oc]
    const int tid = threadIdx.x;
    const int b = blockIdx.z;
    const int r0 = blockIdx.y * 32, c0 = blockIdx.x * 32;
    const float* D = den + b * IMG_HW;
    for (int e = tid; e < 576; e += 256) sW[e] = (e < 288) ? stemw[e] : dw1w[e - 288];
    for (int e = tid; e < 2048; e += 256) sWp[e] = pw1T[e];
    for (int e = tid; e < 35 * 35; e += 256) {
        int li = e / 35, lj = e % 35;
        int gi = r0 - 3 + li, gjj = c0 - 3 + lj;
        sDen[li * 36 + lj] = (gi >= 0 && gjj >= 0) ? D[(gi << 9) + gjj] : 0.0f;
    }
    __syncthreads();

    for (int g = 0; g < 4; ++g) {
        if (g) __syncthreads();
        // phase A: stem for channels 8g..8g+7 at 17x17 positions
        for (int e = tid; e < 2312; e += 256) {      // 289 pos x 8 ch
            int pos = e >> 3, cl = e & 7;
            int sy = pos / 17, sx = pos % 17;
            int c = 8 * g + cl;
            const float* wc = &sW[c * 9];
            const float* dbase = &sDen[(2 * sy) * 36 + 2 * sx];
            float a = 0.0f;
#pragma unroll
            for (int ky = 0; ky < 3; ++ky)
#pragma unroll
                for (int kx = 0; kx < 3; ++kx)
                    a = fmaf(wc[ky * 3 + kx], dbase[ky * 36 + kx], a);
            sStem[cl * 323 + sy * 19 + sx] = silu_f(a);
        }
        __syncthreads();
        // phase B: dw1 for channels 8g..8g+7 -> sDw
        for (int e = tid; e < 512; e += 256) {
            int cl = e >> 6, dy = (e >> 3) & 7, dx = e & 7;
            int c = 8 * g + cl;
            float acc = 0.0f;
#pragma unroll
            for (int ky = 0; ky < 3; ++ky)
#pragma unroll
                for (int kx = 0; kx < 3; ++kx) {
                    int sgy = (r0 >> 1) - 1 + 2 * dy + ky;
                    int sgx = (c0 >> 1) - 1 + 2 * dx + kx;
                    float v = (sgy >= 0 && sgx >= 0)
                        ? sStem[cl * 323 + (2 * dy + ky) * 19 + 2 * dx + kx] : 0.0f;
                    acc = fmaf(sW[288 + c * 9 + ky * 3 + kx], v, acc);
                }
            sDw[c * 64 + (dy << 3) + dx] = silu_f(acc);
        }
    }
    __syncthreads();

    // phase C: pw1 1x1 GEMM 32->64 + SiLU. px = lane, oc-quad = wave.
    const int px = tid & 63, oc0 = (tid >> 6) * 16;
    float acc[16];
#pragma unroll
    for (int j = 0; j < 16; ++j) acc[j] = 0.0f;
    for (int ic = 0; ic < 32; ++ic) {
        float v = sDw[ic * 64 + px];
        const float* wr = &sWp[ic * 64 + oc0];
#pragma unroll
        for (int q = 0; q < 4; ++q) {
            float4 w4 = *(const float4*)(wr + q * 4);
            acc[q * 4 + 0] = fmaf(v, w4.x, acc[q * 4 + 0]);
            acc[q * 4 + 1] = fmaf(v, w4.y, acc[q * 4 + 1]);
            acc[q * 4 + 2] = fmaf(v, w4.z, acc[q * 4 + 2]);
            acc[q * 4 + 3] = fmaf(v, w4.w, acc[q * 4 + 3]);
        }
    }
    const int gpos = ((r0 >> 2) + (px >> 3)) * 128 + (c0 >> 2) + (px & 7);
    float* ob = out + (size_t)b * 64 * 16384 + (size_t)oc0 * 16384 + gpos;
#pragma unroll
    for (int j = 0; j < 16; ++j) ob[(size_t)j * 16384] = silu_f(acc[j]);
}

// ---------------- depthwise 3x3 s2 pad1 + SiLU ----------------
template <int C, int HIN>
__global__ __launch_bounds__(256) void dw_kernel(const float* __restrict__ in,
                                                 const float* __restrict__ w,
                                                 float* __restrict__ out) {
    constexpr int HO = HIN / 2;
    int t = blockIdx.x * 256 + threadIdx.x;       // B*C*HO*HO
    int x = t % HO;
    int y = (t / HO) % HO;
    int c = (t / (HO * HO)) % C;
    int b = t / (HO * HO * C);
    const float* I = in + ((size_t)(b * C + c)) * (HIN * HIN);
    const float* wc = w + c * 9;
    int iy = 2 * y - 1, ix = 2 * x - 1;
    float acc = 0.0f;
#pragma unroll
    for (int ky = 0; ky < 3; ++ky)
#pragma unroll
        for (int kx = 0; kx < 3; ++kx) {
            int yy = iy + ky, xx = ix + kx;
            float vv = (yy >= 0 && xx >= 0) ? I[yy * HIN + xx] : 0.0f;
            acc = fmaf(wc[ky * 3 + kx], vv, acc);
        }
    out[t] = silu_f(acc);
}

// ---------------- depthwise 3x3 s2 + fused 2-way split-K reduce + SiLU input ----------------
template <int C, int HIN>
__global__ __launch_bounds__(256) void dw_reduce2_kernel(const float* __restrict__ part,
                                                         const float* __restrict__ w,
                                                         float* __restrict__ out) {
    constexpr int HO = HIN / 2;
    int t = blockIdx.x * 256 + threadIdx.x;
    int x = t % HO;
    int y = (t / HO) % HO;
    int c = (t / (HO * HO)) % C;
    int b = t / (HO * HO * C);
    const float* Ia = part + ((size_t)(b * C + c)) * (HIN * HIN);
    const float* Ib = Ia + (size_t)BATCH * C * HIN * HIN;
    const float* wc = w + c * 9;
    int iy = 2 * y - 1, ix = 2 * x - 1;
    float acc = 0.0f;
#pragma unroll
    for (int ky = 0; ky < 3; ++ky)
#pragma unroll
        for (int kx = 0; kx < 3; ++kx) {
            int yy = iy + ky, xx = ix + kx;
            float vv = 0.0f;
            if (yy >= 0 && xx >= 0) {
                int o = yy * HIN + xx;
                vv = silu_f(Ia[o] + Ib[o]);
            }
            acc = fmaf(wc[ky * 3 + kx], vv, acc);
        }
    out[t] = silu_f(acc);
}

// ---------------- pointwise 1x1 conv: double-buffered, split-K GEMM ----------------
template <int ICT, int NSIN, int NSPLIT, int OC, bool SILU>
__global__ __launch_bounds__(256) void pw_gemm(const float* __restrict__ in,
                                               const float* __restrict__ wT,
                                               float* __restrict__ out,
                                               int HW) {
    constexpr int KC = 32, TP = 64, TOC = 64, OPT = 4, PPT = 4;
    constexpr int KS = ICT / NSPLIT;
    constexpr int NC = KS / KC;
    constexpr int NOG = TOC / OPT;                // 16
    constexpr int PV4 = KC * TP / 4 / 256;        // 2 float4/thread (px)
    constexpr int WV4 = KC * TOC / 4 / 256;       // 2 float4/thread (w)
    static_assert(KS % KC == 0, "split");
    __shared__ __align__(16) float sPx[2][KC * TP];
    __shared__ __align__(16) float sW[2][KC * TOC];
    const int tid = threadIdx.x;
    const int zb = blockIdx.z;
    const int b = zb / NSPLIT, ks = zb % NSPLIT;
    const int p0 = blockIdx.x * TP;
    const int oc0 = blockIdx.y * TOC;
    const int ocg = tid % NOG, pxg = tid / NOG;   // pxg in [0,16)
    const size_t instride = (size_t)BATCH * ICT * HW;
    const float* gin0 = in + ((size_t)b * ICT + ks * KS) * HW + p0;
    const float* gw0  = wT + ((size_t)(ks * KS)) * OC + oc0;

    float4 rp[PV4], rw[WV4];
    auto load_chunk = [&](int cc) {
        const float* gin = gin0 + (size_t)cc * KC * HW;
#pragma unroll
        for (int i = 0; i < PV4; ++i) {
            int e = tid + i * 256;
            int row = e / (TP / 4), col = e % (TP / 4);
            const float* base = gin + (size_t)row * HW + col * 4;
            float4 a = *(const float4*)base;
#pragma unroll
            for (int s = 1; s < NSIN; ++s) {
                float4 t4 = *(const float4*)(base + (size_t)s * instride);
                a.x += t4.x; a.y += t4.y; a.z += t4.z; a.w += t4.w;
            }
            if (NSIN > 1) {
                a.x = silu_f(a.x); a.y = silu_f(a.y);
                a.z = silu_f(a.z); a.w = silu_f(a.w);
            }
            rp[i] = a;
        }
        const float* gw = gw0 + (size_t)cc * KC * OC;
#pragma unroll
        for (int i = 0; i < WV4; ++i) {
            int e = tid + i * 256;
            int row = e / (TOC / 4), col = e % (TOC / 4);
            rw[i] = *(const float4*)(gw + (size_t)row * OC + col * 4);
        }
    };
    auto store_chunk = [&](int buf) {
#pragma unroll
        for (int i = 0; i < PV4; ++i) ((float4*)sPx[buf])[tid + i * 256] = rp[i];
#pragma unroll
        for (int i = 0; i < WV4; ++i) ((float4*)sW[buf])[tid + i * 256] = rw[i];
    };

    float acc[OPT][PPT];
#pragma unroll
    for (int o = 0; o < OPT; ++o)
#pragma unroll
        for (int p = 0; p < PPT; ++p) acc[o][p] = 0.0f;

    load_chunk(0);
    store_chunk(0);
    __syncthreads();
    for (int cc = 0; cc < NC; ++cc) {
        if (cc + 1 < NC) load_chunk(cc + 1);
        const int buf = cc & 1;
#pragma unroll 4
        for (int k = 0; k < KC; ++k) {
            float4 pv = *(const float4*)&sPx[buf][k * TP + pxg * PPT];
            float4 wv = *(const float4*)&sW[buf][k * TOC + ocg * OPT];
            float w0 = wv.x, w1 = wv.y, w2 = wv.z, w3 = wv.w;
            acc[0][0] = fmaf(pv.x, w0, acc[0][0]);
            acc[0][1] = fmaf(pv.y, w0, acc[0][1]);
            acc[0][2] = fmaf(pv.z, w0, acc[0][2]);
            acc[0][3] = fmaf(pv.w, w0, acc[0][3]);
            acc[1][0] = fmaf(pv.x, w1, acc[1][0]);
            acc[1][1] = fmaf(pv.y, w1, acc[1][1]);
            acc[1][2] = fmaf(pv.z, w1, acc[1][2]);
            acc[1][3] = fmaf(pv.w, w1, acc[1][3]);
            acc[2][0] = fmaf(pv.x, w2, acc[2][0]);
            acc[2][1] = fmaf(pv.y, w2, acc[2][1]);
            acc[2][2] = fmaf(pv.z, w2, acc[2][2]);
            acc[2][3] = fmaf(pv.w, w2, acc[2][3]);
            acc[3][0] = fmaf(pv.x, w3, acc[3][0]);
            acc[3][1] = fmaf(pv.y, w3, acc[3][1]);
            acc[3][2] = fmaf(pv.z, w3, acc[3][2]);
            acc[3][3] = fmaf(pv.w, w3, acc[3][3]);
        }
        if (cc + 1 < NC) {
            store_chunk((cc + 1) & 1);
            __syncthreads();
        }
    }

    float* ob;
    if (NSPLIT == 1)
        ob = out + ((size_t)(b * OC + oc0 + ocg * OPT)) * HW + p0 + pxg * PPT;
    else
        ob = out + (((size_t)(ks * BATCH + b)) * OC + oc0 + ocg * OPT) * HW + p0 + pxg * PPT;
#pragma unroll
    for (int o = 0; o < OPT; ++o) {
        float4 r;
        r.x = SILU ? silu_f(acc[o][0]) : acc[o][0];
        r.y = SILU ? silu_f(acc[o][1]) : acc[o][1];
        r.z = SILU ? silu_f(acc[o][2]) : acc[o][2];
        r.w = SILU ? silu_f(acc[o][3]) : acc[o][3];
        *(float4*)(ob + (size_t)o * HW) = r;
    }
}

// ---------------- prep: weight transposes + combined tail weights ----------------
__global__ __launch_bounds__(256) void prep_kernel(const float* __restrict__ pw1,
                                                   const float* __restrict__ pw2,
                                                   const float* __restrict__ pw3,
                                                   const float* __restrict__ pw4,
                                                   const float* __restrict__ headw,
                                                   const float* __restrict__ projw,
                                                   const float* __restrict__ projb,
                                                   const float* __restrict__ finalw,
                                                   const float* __restrict__ finalb,
                                                   float* __restrict__ ws) {
    int t = blockIdx.x * 256 + threadIdx.x;
    if (t < 2048) {                                  // pw1: 64x32 -> [32][64]
        int e = t; int ic = e >> 6, oc = e & 63;
        ws[O_WT1 + e] = pw1[oc * 32 + ic];
    } else if (t < 10240) {                          // pw2: 128x64 -> [64][128]
        int e = t - 2048; int ic = e >> 7, oc = e & 127;
        ws[O_WT2 + e] = pw2[oc * 64 + ic];
    } else if (t < 43008) {                          // pw3: 256x128 -> [128][256]
        int e = t - 10240; int ic = e >> 8, oc = e & 255;
        ws[O_WT3 + e] = pw3[oc * 128 + ic];
    } else if (t < 174080) {                         // pw4: 512x256 -> [256][512]
        int e = t - 43008; int ic = e >> 9, oc = e & 511;
        ws[O_WT4 + e] = pw4[oc * 256 + ic];
    } else if (t < 829440) {                         // head: 1280x512 -> [512][1280]
        int e = t - 174080; int ic = e / 1280, oc = e % 1280;
        ws[O_WTH + e] = headw[oc * 512 + ic];
    } else if (t < 830720) {                         // w_comb[k] = sum_ch fw[ch]*proj_w[ch,k]
        int k = t - 829440;
        float a = 0.0f;
        for (int ch = 0; ch < 64; ++ch) a = fmaf(finalw[ch], projw[ch * 1280 + k], a);
        ws[O_WCOMB + k] = a;
    } else if (t == 830720) {                        // b_comb = dot(fw, proj_b)
        float a = 0.0f;
        for (int ch = 0; ch < 64; ++ch) a = fmaf(finalw[ch], projb[ch], a);
        ws[O_BCOMB] = a;
    }
}

// ---------------- fused head-partial reduce (4-way) + SiLU + wcomb dot ----------------
__global__ __launch_bounds__(256) void tail_head(const float* __restrict__ part,
                                                 const float* __restrict__ wcomb,
                                                 const float* __restrict__ bcomb,
                                                 float* __restrict__ s) {
    __shared__ float red[256];
    constexpr size_t PS = (size_t)4 * 1280 * 256;  // per-split stride
    int b = blockIdx.x >> 4;                      // 64 blocks: 4 batch x 16 px-groups
    int px0 = (blockIdx.x & 15) << 4;
    int px = threadIdx.x & 15, kg = threadIdx.x >> 4;   // 16 k-groups of 80
    const float* h0 = part + (size_t)b * 1280 * 256 + px0 + px;
    float acc = 0.0f;
    int k0 = kg * 80;
    for (int k = k0; k < k0 + 80; ++k) {
        size_t off = (size_t)k * 256;
        float v = silu_f(h0[off] + h0[off + PS] + h0[off + 2 * PS] + h0[off + 3 * PS]);
        acc = fmaf(wcomb[k], v, acc);
    }
    red[threadIdx.x] = acc;
    __syncthreads();
    if (threadIdx.x < 16) {
        float a = bcomb[0];
#pragma unroll
        for (int g = 0; g < 16; ++g) a += red[g * 16 + threadIdx.x];
        s[b * 256 + px0 + threadIdx.x] = a;
    }
}

// ---------------- fused bilinear(16->512) + 2-level Haar LL + final bias ----------------
__global__ __launch_bounds__(256) void resize_haar(const float* __restrict__ s,
                                                   const float* __restrict__ finalb,
                                                   float* __restrict__ out) {
    int t = blockIdx.x * 256 + threadIdx.x;       // 4*128*128
    int c = t & 127, r = (t >> 7) & 127, b = t >> 14;
    const float* S = s + b * 256;
    float acc = 0.0f;
#pragma unroll
    for (int j = 0; j < 4; ++j) {
        float sy = ((4 * r + j) + 0.5f) * (1.0f / 32.0f) - 0.5f;
        int y0 = (int)floorf(sy);
        float fy = sy - (float)y0;
        int ya = y0 < 0 ? 0 : y0;
        int yb = (y0 + 1) > 15 ? 15 : (y0 + 1);
#pragma unroll
        for (int i = 0; i < 4; ++i) {
            float sx = ((4 * c + i) + 0.5f) * (1.0f / 32.0f) - 0.5f;
            int x0 = (int)floorf(sx);
            float fx = sx - (float)x0;
            int xa = x0 < 0 ? 0 : x0;
            int xb = (x0 + 1) > 15 ? 15 : (x0 + 1);
            float v0 = S[ya * 16 + xa] * (1.0f - fx) + S[ya * 16 + xb] * fx;
            float v1 = S[yb * 16 + xa] * (1.0f - fx) + S[yb * 16 + xb] * fx;
            acc += v0 * (1.0f - fy) + v1 * fy;
        }
    }
    out[t] = 0.25f * acc + finalb[0];
}

// ---------------- launch ----------------
extern "C" void kernel_launch(void* const* d_in, const int* in_sizes, int n_in,
                              void* d_out, int out_size, void* d_ws, size_t ws_size,
                              hipStream_t stream) {
    if (ws_size < WS_FLOATS * sizeof(float)) return;

    const float* img    = (const float*)d_in[0];
    const float* stem_w = (const float*)d_in[1];
    const float* dw1_w  = (const float*)d_in[2];
    const float* pw1_w  = (const float*)d_in[3];
    const float* dw2_w  = (const float*)d_in[4];
    const float* pw2_w  = (const float*)d_in[5];
    const float* dw3_w  = (const float*)d_in[6];
    const float* pw3_w  = (const float*)d_in[7];
    const float* dw4_w  = (const float*)d_in[8];
    const float* pw4_w  = (const float*)d_in[9];
    const float* head_w = (const float*)d_in[10];
    const float* proj_w = (const float*)d_in[11];
    const float* proj_b = (const float*)d_in[12];
    const float* final_w= (const float*)d_in[13];
    const float* final_b= (const float*)d_in[14];
    float* ws  = (float*)d_ws;
    float* out = (float*)d_out;

    // weight prep
    prep_kernel<<<3246, 256, 0, stream>>>(pw1_w, pw2_w, pw3_w, pw4_w, head_w,
                                          proj_w, proj_b, final_w, final_b, ws);

    // TV Chambolle: 20 iterations in 2 register-resident launches (10+10).
    dim3 tvg(12, 16, 4);                           // 44-col x 32-row output tiles (768 blocks)
    tv_reg<10, true,  false><<<tvg, 256, 0, stream>>>(img, img,       ws + O_PA);  // 1-10
    tv_reg<10, false, true ><<<tvg, 256, 0, stream>>>(img, ws + O_PA, ws + O_DEN); // 11-20 -> den

    // fused stem + dw1 + pw1 (den -> [B][64][128][128])
    stem_dw1_pw1<<<dim3(16, 16, 4), 256, 0, stream>>>(ws + O_DEN, stem_w, dw1_w,
                                                      ws + O_WT1, ws + O_A1);

    // backbone
    dw_kernel<64, 128><<<4096, 256, 0, stream>>>(ws + O_A1, dw2_w, ws + O_A2);
    pw_gemm<64, 1, 2, 128, false><<<dim3(64, 2, 8), 256, 0, stream>>>(ws + O_A2, ws + O_WT2, ws + O_PA, 4096);

    dw_reduce2_kernel<128, 64><<<2048, 256, 0, stream>>>(ws + O_PA, dw3_w, ws + O_A1);
    pw_gemm<128, 1, 2, 256, false><<<dim3(16, 4, 8), 256, 0, stream>>>(ws + O_A1, ws + O_WT3, ws + O_PA, 1024);

    dw_reduce2_kernel<256, 32><<<1024, 256, 0, stream>>>(ws + O_PA, dw4_w, ws + O_A2);
    pw_gemm<256, 1, 4, 512, false><<<dim3(4, 8, 16), 256, 0, stream>>>(ws + O_A2, ws + O_WT4, ws + O_PA, 256);

    // head 512->1280 @16x16: fused 4-way partial reduce+SiLU at staging, split-4 raw out -> A1
    pw_gemm<512, 4, 4, 1280, false><<<dim3(4, 20, 16), 256, 0, stream>>>(ws + O_PA, ws + O_WTH, ws + O_A1, 256);
    tail_head<<<64, 256, 0, stream>>>(ws + O_A1, ws + O_WCOMB, ws + O_BCOMB, ws + O_S);

    resize_haar<<<256, 256, 0, stream>>>(ws + O_S, final_b, out);
}

// Round 13
// 291.846 us; speedup vs baseline: 1.0629x; 1.0024x over previous
//
#include <hip/hip_runtime.h>
#include <math.h>

// ---------------- problem constants ----------------
constexpr int BATCH = 4;
constexpr int IMG_H = 512, IMG_W = 512;
constexpr int IMG_HW = IMG_H * IMG_W;          // 262144
constexpr int PSTR = BATCH * IMG_HW;           // p-plane stride 1048576

// ---------------- workspace layout (floats) ----------------
constexpr size_t O_PA   = 0;                       // p ping [2][4][512][512] (also split-K partial arena)
constexpr size_t O_PB   = O_PA + 2 * (size_t)PSTR; // p pong
constexpr size_t O_DEN  = O_PB + 2 * (size_t)PSTR; // denoised [4][512][512]
constexpr size_t O_A1   = O_DEN + (size_t)PSTR;    // arena1 (8388608 floats; also head-partial arena)
constexpr size_t O_A2   = O_A1 + 8388608;          // arena2 (2097152 floats)
constexpr size_t O_WT1  = O_A2 + 2097152;          // wT pw1  [32][64]
constexpr size_t O_WT2  = O_WT1 + 32 * 64;
constexpr size_t O_WT3  = O_WT2 + 64 * 128;
constexpr size_t O_WT4  = O_WT3 + 128 * 256;
constexpr size_t O_WTH  = O_WT4 + 256 * 512;
constexpr size_t O_WCOMB= O_WTH + 512 * 1280;      // [1280]
constexpr size_t O_BCOMB= O_WCOMB + 1280;          // [1]
constexpr size_t O_S    = O_BCOMB + 4;             // s field [4][16][16]
constexpr size_t WS_FLOATS = O_S + 1024;

__device__ __forceinline__ float silu_f(float x) {
    return x / (1.0f + expf(-x));
}
__device__ __forceinline__ int clampi(int v, int lo, int hi) {
    return v < lo ? lo : (v > hi ? hi : v);
}

// ---------------- TV Chambolle: register-resident, shuffle-exchange ----------------
// Same 44x32 output tile / halo-10 as R12, but 512-thread blocks (8 waves,
// ROWS=7, 56 rows computed for 52 needed): TV is LATENCY-bound on the
// shfl(DS)->sqrt->rcp chain (R12: 43.6us at VALUBusy 58%, 3 waves/SIMD vs
// ~7us of pure VALU work). 8 waves/block doubles resident waves at +7.7%
// work (vs R11's 16-row tile which cost 1.38x work). Validity erosion:
// rows [10,46) after 10 iters covers output rows [10,42); lanes [10,54).
// Halo garbage finite, never read by valid cells (guards / interior proof).
template <int NST, bool FIRST, bool LAST>
__global__ __launch_bounds__(512) void tv_reg(const float* __restrict__ img,
                                              const float* __restrict__ pin,
                                              float* __restrict__ pout) {
    constexpr int ROWS = 7, NW = 8, HL = 10, TC = 44, TR = 32;
    __shared__ float bndP[512], bndO[512];
    const int tid = threadIdx.x;
    const int lane = tid & 63, w = tid >> 6;
    const int b = blockIdx.z;
    const int r0 = blockIdx.y * TR, c0 = blockIdx.x * TC;
    const int gj = c0 - HL + lane;
    const int gjc = clampi(gj, 0, 511);
    const int gib = r0 - HL + w * ROWS;
    const float* I = img + b * IMG_HW;
    const bool interior = (r0 - HL >= 1) && (r0 + NW * ROWS - HL <= 511) &&
                          (c0 - HL >= 1) && (c0 + 64 - HL <= 511);

    float rim[ROWS], rp0[ROWS], rp1[ROWS], ro[ROWS];
#pragma unroll
    for (int k = 0; k < ROWS; ++k) {
        int gi = clampi(gib + k, 0, 511);
        rim[k] = I[(gi << 9) + gjc];
    }
    if (!FIRST) {
        const float* P0 = pin + b * IMG_HW;
        const float* P1 = pin + PSTR + b * IMG_HW;
#pragma unroll
        for (int k = 0; k < ROWS; ++k) {
            int gi = clampi(gib + k, 0, 511);
            rp0[k] = P0[(gi << 9) + gjc];
            rp1[k] = P1[(gi << 9) + gjc];
        }
    }
    const bool gjpos = (gj > 0), gjlt = (gj < 511);

    int s0 = 0;
    if (FIRST) {
        // stage 0 specialized: p == 0  =>  out-field == img
        bndO[tid] = rim[0];
        __syncthreads();
        float odn = (w < NW - 1) ? bndO[tid + 64] : 0.0f;
        if (interior) {
#pragma unroll
            for (int k = 0; k < ROWS; ++k) {
                float oR = __shfl_down(rim[k], 1);
                float od = (k < ROWS - 1) ? rim[k + 1] : odn;
                float gy = od - rim[k];
                float gx = oR - rim[k];
                float inv = 1.0f / (1.0f + 2.5f * sqrtf(gy * gy + gx * gx));
                rp0[k] = -0.25f * gy * inv;
                rp1[k] = -0.25f * gx * inv;
            }
        } else {
#pragma unroll
            for (int k = 0; k < ROWS; ++k) {
                float oR = __shfl_down(rim[k], 1);
                float od = (k < ROWS - 1) ? rim[k + 1] : odn;
                int gi = gib + k;
                float gy = (gi < 511) ? od - rim[k] : 0.0f;
                float gx = gjlt ? oR - rim[k] : 0.0f;
                float inv = 1.0f / (1.0f + 2.5f * sqrtf(gy * gy + gx * gx));
                rp0[k] = -0.25f * gy * inv;
                rp1[k] = -0.25f * gx * inv;
            }
        }
        s0 = 1;
    }

    for (int s = s0; s < NST; ++s) {
        __syncthreads();                 // bndO(s-1) readers done before rewrite
        bndP[tid] = rp0[ROWS - 1];
        __syncthreads();
        float pup0 = (w > 0) ? bndP[tid - 64] : 0.0f;
        if (interior) {
#pragma unroll
            for (int k = 0; k < ROWS; ++k) {
                float p1l = __shfl_up(rp1[k], 1);
                float pup = (k > 0) ? rp0[k - 1] : pup0;
                ro[k] = rim[k] - rp0[k] - rp1[k] + pup + p1l;
            }
            bndO[tid] = ro[0];
            __syncthreads();
            float odn = (w < NW - 1) ? bndO[tid + 64] : 0.0f;
#pragma unroll
            for (int k = 0; k < ROWS; ++k) {
                float oR = __shfl_down(ro[k], 1);
                float od = (k < ROWS - 1) ? ro[k + 1] : odn;
                float gy = od - ro[k];
                float gx = oR - ro[k];
                float inv = 1.0f / (1.0f + 2.5f * sqrtf(gy * gy + gx * gx));
                rp0[k] = (rp0[k] - 0.25f * gy) * inv;
                rp1[k] = (rp1[k] - 0.25f * gx) * inv;
            }
        } else {
#pragma unroll
            for (int k = 0; k < ROWS; ++k) {
                float p1l = __shfl_up(rp1[k], 1);
                float o = rim[k] - rp0[k] - rp1[k];
                float pup = (k > 0) ? rp0[k - 1] : pup0;
                int gi = gib + k;
                if (gi > 0) o += pup;
                if (gjpos) o += p1l;
                ro[k] = o;
            }
            bndO[tid] = ro[0];
            __syncthreads();
            float odn = (w < NW - 1) ? bndO[tid + 64] : 0.0f;
#pragma unroll
            for (int k = 0; k < ROWS; ++k) {
                float oR = __shfl_down(ro[k], 1);
                float od = (k < ROWS - 1) ? ro[k + 1] : odn;
                int gi = gib + k;
                float gy = (gi < 511) ? od - ro[k] : 0.0f;
                float gx = gjlt ? oR - ro[k] : 0.0f;
                float inv = 1.0f / (1.0f + 2.5f * sqrtf(gy * gy + gx * gx));
                rp0[k] = (rp0[k] - 0.25f * gy) * inv;
                rp1[k] = (rp1[k] - 0.25f * gx) * inv;
            }
        }
    }

    const bool cst = (lane >= HL && lane < HL + TC && gj < 512);
    if (LAST) {
        // den = img + div(p) on output tile
        __syncthreads();
        bndP[tid] = rp0[ROWS - 1];
        __syncthreads();
        float pup0 = (w > 0) ? bndP[tid - 64] : 0.0f;
        float* D = pout + b * IMG_HW;
#pragma unroll
        for (int k = 0; k < ROWS; ++k) {
            float p1l = __shfl_up(rp1[k], 1);
            int gi = gib + k;
            int rk = w * ROWS + k;
            float o = rim[k] - rp0[k] - rp1[k];
            float pup = (k > 0) ? rp0[k - 1] : pup0;
            if (gi > 0) o += pup;
            if (gjpos) o += p1l;
            if (rk >= HL && rk < HL + TR && cst) D[(gi << 9) + gj] = o;
        }
    } else {
        float* Q0 = pout + b * IMG_HW;
        float* Q1 = pout + PSTR + b * IMG_HW;
#pragma unroll
        for (int k = 0; k < ROWS; ++k) {
            int rk = w * ROWS + k;
            int gi = gib + k;
            if (rk >= HL && rk < HL + TR && cst) {
                Q0[(gi << 9) + gj] = rp0[k];
                Q1[(gi << 9) + gj] = rp1[k];
            }
        }
    }
}

// ---------------- fused stem (3x3 s2 + SiLU) + dw1 (3x3 s2 + SiLU) + pw1 (1x1 32->64 + SiLU) ----
__global__ __launch_bounds__(256) void stem_dw1_pw1(const float* __restrict__ den,
                                                    const float* __restrict__ stemw,
                                                    const float* __restrict__ dw1w,
                                                    const float* __restrict__ pw1T,
                                                    float* __restrict__ out) {
    __shared__ float sDen[35 * 36];
    __shared__ float sStem[8 * 323];   // 8 ch x (17 rows x stride 19)
    __shared__ float sDw[32 * 64];     // dw1 out: [ic][px], px = dy*8+dx
    __shared__ float sW[576];
    __shared__ __align__(16) float sWp[2048];  // pw1T [ic][oc]
    const int tid = threadIdx.x;
    const int b = blockIdx.z;
    const int r0 = blockIdx.y * 32, c0 = blockIdx.x * 32;
    const float* D = den + b * IMG_HW;
    for (int e = tid; e < 576; e += 256) sW[e] = (e < 288) ? stemw[e] : dw1w[e - 288];
    for (int e = tid; e < 2048; e += 256) sWp[e] = pw1T[e];
    for (int e = tid; e < 35 * 35; e += 256) {
        int li = e / 35, lj = e % 35;
        int gi = r0 - 3 + li, gjj = c0 - 3 + lj;
        sDen[li * 36 + lj] = (gi >= 0 && gjj >= 0) ? D[(gi << 9) + gjj] : 0.0f;
    }
    __syncthreads();

    for (int g = 0; g < 4; ++g) {
        if (g) __syncthreads();
        // phase A: stem for channels 8g..8g+7 at 17x17 positions
        for (int e = tid; e < 2312; e += 256) {      // 289 pos x 8 ch
            int pos = e >> 3, cl = e & 7;
            int sy = pos / 17, sx = pos % 17;
            int c = 8 * g + cl;
            const float* wc = &sW[c * 9];
            const float* dbase = &sDen[(2 * sy) * 36 + 2 * sx];
            float a = 0.0f;
#pragma unroll
            for (int ky = 0; ky < 3; ++ky)
#pragma unroll
                for (int kx = 0; kx < 3; ++kx)
                    a = fmaf(wc[ky * 3 + kx], dbase[ky * 36 + kx], a);
            sStem[cl * 323 + sy * 19 + sx] = silu_f(a);
        }
        __syncthreads();
        // phase B: dw1 for channels 8g..8g+7 -> sDw
        for (int e = tid; e < 512; e += 256) {
            int cl = e >> 6, dy = (e >> 3) & 7, dx = e & 7;
            int c = 8 * g + cl;
            float acc = 0.0f;
#pragma unroll
            for (int ky = 0; ky < 3; ++ky)
#pragma unroll
                for (int kx = 0; kx < 3; ++kx) {
                    int sgy = (r0 >> 1) - 1 + 2 * dy + ky;
                    int sgx = (c0 >> 1) - 1 + 2 * dx + kx;
                    float v = (sgy >= 0 && sgx >= 0)
                        ? sStem[cl * 323 + (2 * dy + ky) * 19 + 2 * dx + kx] : 0.0f;
                    acc = fmaf(sW[288 + c * 9 + ky * 3 + kx], v, acc);
                }
            sDw[c * 64 + (dy << 3) + dx] = silu_f(acc);
        }
    }
    __syncthreads();

    // phase C: pw1 1x1 GEMM 32->64 + SiLU. px = lane, oc-quad = wave.
    const int px = tid & 63, oc0 = (tid >> 6) * 16;
    float acc[16];
#pragma unroll
    for (int j = 0; j < 16; ++j) acc[j] = 0.0f;
    for (int ic = 0; ic < 32; ++ic) {
        float v = sDw[ic * 64 + px];
        const float* wr = &sWp[ic * 64 + oc0];
#pragma unroll
        for (int q = 0; q < 4; ++q) {
            float4 w4 = *(const float4*)(wr + q * 4);
            acc[q * 4 + 0] = fmaf(v, w4.x, acc[q * 4 + 0]);
            acc[q * 4 + 1] = fmaf(v, w4.y, acc[q * 4 + 1]);
            acc[q * 4 + 2] = fmaf(v, w4.z, acc[q * 4 + 2]);
            acc[q * 4 + 3] = fmaf(v, w4.w, acc[q * 4 + 3]);
        }
    }
    const int gpos = ((r0 >> 2) + (px >> 3)) * 128 + (c0 >> 2) + (px & 7);
    float* ob = out + (size_t)b * 64 * 16384 + (size_t)oc0 * 16384 + gpos;
#pragma unroll
    for (int j = 0; j < 16; ++j) ob[(size_t)j * 16384] = silu_f(acc[j]);
}

// ---------------- depthwise 3x3 s2 pad1 + SiLU ----------------
template <int C, int HIN>
__global__ __launch_bounds__(256) void dw_kernel(const float* __restrict__ in,
                                                 const float* __restrict__ w,
                                                 float* __restrict__ out) {
    constexpr int HO = HIN / 2;
    int t = blockIdx.x * 256 + threadIdx.x;       // B*C*HO*HO
    int x = t % HO;
    int y = (t / HO) % HO;
    int c = (t / (HO * HO)) % C;
    int b = t / (HO * HO * C);
    const float* I = in + ((size_t)(b * C + c)) * (HIN * HIN);
    const float* wc = w + c * 9;
    int iy = 2 * y - 1, ix = 2 * x - 1;
    float acc = 0.0f;
#pragma unroll
    for (int ky = 0; ky < 3; ++ky)
#pragma unroll
        for (int kx = 0; kx < 3; ++kx) {
            int yy = iy + ky, xx = ix + kx;
            float vv = (yy >= 0 && xx >= 0) ? I[yy * HIN + xx] : 0.0f;
            acc = fmaf(wc[ky * 3 + kx], vv, acc);
        }
    out[t] = silu_f(acc);
}

// ---------------- depthwise 3x3 s2 + fused 2-way split-K reduce + SiLU input ----------------
template <int C, int HIN>
__global__ __launch_bounds__(256) void dw_reduce2_kernel(const float* __restrict__ part,
                                                         const float* __restrict__ w,
                                                         float* __restrict__ out) {
    constexpr int HO = HIN / 2;
    int t = blockIdx.x * 256 + threadIdx.x;
    int x = t % HO;
    int y = (t / HO) % HO;
    int c = (t / (HO * HO)) % C;
    int b = t / (HO * HO * C);
    const float* Ia = part + ((size_t)(b * C + c)) * (HIN * HIN);
    const float* Ib = Ia + (size_t)BATCH * C * HIN * HIN;
    const float* wc = w + c * 9;
    int iy = 2 * y - 1, ix = 2 * x - 1;
    float acc = 0.0f;
#pragma unroll
    for (int ky = 0; ky < 3; ++ky)
#pragma unroll
        for (int kx = 0; kx < 3; ++kx) {
            int yy = iy + ky, xx = ix + kx;
            float vv = 0.0f;
            if (yy >= 0 && xx >= 0) {
                int o = yy * HIN + xx;
                vv = silu_f(Ia[o] + Ib[o]);
            }
            acc = fmaf(wc[ky * 3 + kx], vv, acc);
        }
    out[t] = silu_f(acc);
}

// ---------------- pointwise 1x1 conv: double-buffered, split-K GEMM ----------------
template <int ICT, int NSIN, int NSPLIT, int OC, bool SILU>
__global__ __launch_bounds__(256) void pw_gemm(const float* __restrict__ in,
                                               const float* __restrict__ wT,
                                               float* __restrict__ out,
                                               int HW) {
    constexpr int KC = 32, TP = 64, TOC = 64, OPT = 4, PPT = 4;
    constexpr int KS = ICT / NSPLIT;
    constexpr int NC = KS / KC;
    constexpr int NOG = TOC / OPT;                // 16
    constexpr int PV4 = KC * TP / 4 / 256;        // 2 float4/thread (px)
    constexpr int WV4 = KC * TOC / 4 / 256;       // 2 float4/thread (w)
    static_assert(KS % KC == 0, "split");
    __shared__ __align__(16) float sPx[2][KC * TP];
    __shared__ __align__(16) float sW[2][KC * TOC];
    const int tid = threadIdx.x;
    const int zb = blockIdx.z;
    const int b = zb / NSPLIT, ks = zb % NSPLIT;
    const int p0 = blockIdx.x * TP;
    const int oc0 = blockIdx.y * TOC;
    const int ocg = tid % NOG, pxg = tid / NOG;   // pxg in [0,16)
    const size_t instride = (size_t)BATCH * ICT * HW;
    const float* gin0 = in + ((size_t)b * ICT + ks * KS) * HW + p0;
    const float* gw0  = wT + ((size_t)(ks * KS)) * OC + oc0;

    float4 rp[PV4], rw[WV4];
    auto load_chunk = [&](int cc) {
        const float* gin = gin0 + (size_t)cc * KC * HW;
#pragma unroll
        for (int i = 0; i < PV4; ++i) {
            int e = tid + i * 256;
            int row = e / (TP / 4), col = e % (TP / 4);
            const float* base = gin + (size_t)row * HW + col * 4;
            float4 a = *(const float4*)base;
#pragma unroll
            for (int s = 1; s < NSIN; ++s) {
                float4 t4 = *(const float4*)(base + (size_t)s * instride);
                a.x += t4.x; a.y += t4.y; a.z += t4.z; a.w += t4.w;
            }
            if (NSIN > 1) {
                a.x = silu_f(a.x); a.y = silu_f(a.y);
                a.z = silu_f(a.z); a.w = silu_f(a.w);
            }
            rp[i] = a;
        }
        const float* gw = gw0 + (size_t)cc * KC * OC;
#pragma unroll
        for (int i = 0; i < WV4; ++i) {
            int e = tid + i * 256;
            int row = e / (TOC / 4), col = e % (TOC / 4);
            rw[i] = *(const float4*)(gw + (size_t)row * OC + col * 4);
        }
    };
    auto store_chunk = [&](int buf) {
#pragma unroll
        for (int i = 0; i < PV4; ++i) ((float4*)sPx[buf])[tid + i * 256] = rp[i];
#pragma unroll
        for (int i = 0; i < WV4; ++i) ((float4*)sW[buf])[tid + i * 256] = rw[i];
    };

    float acc[OPT][PPT];
#pragma unroll
    for (int o = 0; o < OPT; ++o)
#pragma unroll
        for (int p = 0; p < PPT; ++p) acc[o][p] = 0.0f;

    load_chunk(0);
    store_chunk(0);
    __syncthreads();
    for (int cc = 0; cc < NC; ++cc) {
        if (cc + 1 < NC) load_chunk(cc + 1);
        const int buf = cc & 1;
#pragma unroll 4
        for (int k = 0; k < KC; ++k) {
            float4 pv = *(const float4*)&sPx[buf][k * TP + pxg * PPT];
            float4 wv = *(const float4*)&sW[buf][k * TOC + ocg * OPT];
            float w0 = wv.x, w1 = wv.y, w2 = wv.z, w3 = wv.w;
            acc[0][0] = fmaf(pv.x, w0, acc[0][0]);
            acc[0][1] = fmaf(pv.y, w0, acc[0][1]);
            acc[0][2] = fmaf(pv.z, w0, acc[0][2]);
            acc[0][3] = fmaf(pv.w, w0, acc[0][3]);
            acc[1][0] = fmaf(pv.x, w1, acc[1][0]);
            acc[1][1] = fmaf(pv.y, w1, acc[1][1]);
            acc[1][2] = fmaf(pv.z, w1, acc[1][2]);
            acc[1][3] = fmaf(pv.w, w1, acc[1][3]);
            acc[2][0] = fmaf(pv.x, w2, acc[2][0]);
            acc[2][1] = fmaf(pv.y, w2, acc[2][1]);
            acc[2][2] = fmaf(pv.z, w2, acc[2][2]);
            acc[2][3] = fmaf(pv.w, w2, acc[2][3]);
            acc[3][0] = fmaf(pv.x, w3, acc[3][0]);
            acc[3][1] = fmaf(pv.y, w3, acc[3][1]);
            acc[3][2] = fmaf(pv.z, w3, acc[3][2]);
            acc[3][3] = fmaf(pv.w, w3, acc[3][3]);
        }
        if (cc + 1 < NC) {
            store_chunk((cc + 1) & 1);
            __syncthreads();
        }
    }

    float* ob;
    if (NSPLIT == 1)
        ob = out + ((size_t)(b * OC + oc0 + ocg * OPT)) * HW + p0 + pxg * PPT;
    else
        ob = out + (((size_t)(ks * BATCH + b)) * OC + oc0 + ocg * OPT) * HW + p0 + pxg * PPT;
#pragma unroll
    for (int o = 0; o < OPT; ++o) {
        float4 r;
        r.x = SILU ? silu_f(acc[o][0]) : acc[o][0];
        r.y = SILU ? silu_f(acc[o][1]) : acc[o][1];
        r.z = SILU ? silu_f(acc[o][2]) : acc[o][2];
        r.w = SILU ? silu_f(acc[o][3]) : acc[o][3];
        *(float4*)(ob + (size_t)o * HW) = r;
    }
}

// ---------------- prep: weight transposes + combined tail weights ----------------
__global__ __launch_bounds__(256) void prep_kernel(const float* __restrict__ pw1,
                                                   const float* __restrict__ pw2,
                                                   const float* __restrict__ pw3,
                                                   const float* __restrict__ pw4,
                                                   const float* __restrict__ headw,
                                                   const float* __restrict__ projw,
                                                   const float* __restrict__ projb,
                                                   const float* __restrict__ finalw,
                                                   const float* __restrict__ finalb,
                                                   float* __restrict__ ws) {
    int t = blockIdx.x * 256 + threadIdx.x;
    if (t < 2048) {                                  // pw1: 64x32 -> [32][64]
        int e = t; int ic = e >> 6, oc = e & 63;
        ws[O_WT1 + e] = pw1[oc * 32 + ic];
    } else if (t < 10240) {                          // pw2: 128x64 -> [64][128]
        int e = t - 2048; int ic = e >> 7, oc = e & 127;
        ws[O_WT2 + e] = pw2[oc * 64 + ic];
    } else if (t < 43008) {                          // pw3: 256x128 -> [128][256]
        int e = t - 10240; int ic = e >> 8, oc = e & 255;
        ws[O_WT3 + e] = pw3[oc * 128 + ic];
    } else if (t < 174080) {                         // pw4: 512x256 -> [256][512]
        int e = t - 43008; int ic = e >> 9, oc = e & 511;
        ws[O_WT4 + e] = pw4[oc * 256 + ic];
    } else if (t < 829440) {                         // head: 1280x512 -> [512][1280]
        int e = t - 174080; int ic = e / 1280, oc = e % 1280;
        ws[O_WTH + e] = headw[oc * 512 + ic];
    } else if (t < 830720) {                         // w_comb[k] = sum_ch fw[ch]*proj_w[ch,k]
        int k = t - 829440;
        float a = 0.0f;
        for (int ch = 0; ch < 64; ++ch) a = fmaf(finalw[ch], projw[ch * 1280 + k], a);
        ws[O_WCOMB + k] = a;
    } else if (t == 830720) {                        // b_comb = dot(fw, proj_b)
        float a = 0.0f;
        for (int ch = 0; ch < 64; ++ch) a = fmaf(finalw[ch], projb[ch], a);
        ws[O_BCOMB] = a;
    }
}

// ---------------- fused head-partial reduce (4-way) + SiLU + wcomb dot ----------------
__global__ __launch_bounds__(256) void tail_head(const float* __restrict__ part,
                                                 const float* __restrict__ wcomb,
                                                 const float* __restrict__ bcomb,
                                                 float* __restrict__ s) {
    __shared__ float red[256];
    constexpr size_t PS = (size_t)4 * 1280 * 256;  // per-split stride
    int b = blockIdx.x >> 4;                      // 64 blocks: 4 batch x 16 px-groups
    int px0 = (blockIdx.x & 15) << 4;
    int px = threadIdx.x & 15, kg = threadIdx.x >> 4;   // 16 k-groups of 80
    const float* h0 = part + (size_t)b * 1280 * 256 + px0 + px;
    float acc = 0.0f;
    int k0 = kg * 80;
    for (int k = k0; k < k0 + 80; ++k) {
        size_t off = (size_t)k * 256;
        float v = silu_f(h0[off] + h0[off + PS] + h0[off + 2 * PS] + h0[off + 3 * PS]);
        acc = fmaf(wcomb[k], v, acc);
    }
    red[threadIdx.x] = acc;
    __syncthreads();
    if (threadIdx.x < 16) {
        float a = bcomb[0];
#pragma unroll
        for (int g = 0; g < 16; ++g) a += red[g * 16 + threadIdx.x];
        s[b * 256 + px0 + threadIdx.x] = a;
    }
}

// ---------------- fused bilinear(16->512) + 2-level Haar LL + final bias ----------------
__global__ __launch_bounds__(256) void resize_haar(const float* __restrict__ s,
                                                   const float* __restrict__ finalb,
                                                   float* __restrict__ out) {
    int t = blockIdx.x * 256 + threadIdx.x;       // 4*128*128
    int c = t & 127, r = (t >> 7) & 127, b = t >> 14;
    const float* S = s + b * 256;
    float acc = 0.0f;
#pragma unroll
    for (int j = 0; j < 4; ++j) {
        float sy = ((4 * r + j) + 0.5f) * (1.0f / 32.0f) - 0.5f;
        int y0 = (int)floorf(sy);
        float fy = sy - (float)y0;
        int ya = y0 < 0 ? 0 : y0;
        int yb = (y0 + 1) > 15 ? 15 : (y0 + 1);
#pragma unroll
        for (int i = 0; i < 4; ++i) {
            float sx = ((4 * c + i) + 0.5f) * (1.0f / 32.0f) - 0.5f;
            int x0 = (int)floorf(sx);
            float fx = sx - (float)x0;
            int xa = x0 < 0 ? 0 : x0;
            int xb = (x0 + 1) > 15 ? 15 : (x0 + 1);
            float v0 = S[ya * 16 + xa] * (1.0f - fx) + S[ya * 16 + xb] * fx;
            float v1 = S[yb * 16 + xa] * (1.0f - fx) + S[yb * 16 + xb] * fx;
            acc += v0 * (1.0f - fy) + v1 * fy;
        }
    }
    out[t] = 0.25f * acc + finalb[0];
}

// ---------------- launch ----------------
extern "C" void kernel_launch(void* const* d_in, const int* in_sizes, int n_in,
                              void* d_out, int out_size, void* d_ws, size_t ws_size,
                              hipStream_t stream) {
    if (ws_size < WS_FLOATS * sizeof(float)) return;

    const float* img    = (const float*)d_in[0];
    const float* stem_w = (const float*)d_in[1];
    const float* dw1_w  = (const float*)d_in[2];
    const float* pw1_w  = (const float*)d_in[3];
    const float* dw2_w  = (const float*)d_in[4];
    const float* pw2_w  = (const float*)d_in[5];
    const float* dw3_w  = (const float*)d_in[6];
    const float* pw3_w  = (const float*)d_in[7];
    const float* dw4_w  = (const float*)d_in[8];
    const float* pw4_w  = (const float*)d_in[9];
    const float* head_w = (const float*)d_in[10];
    const float* proj_w = (const float*)d_in[11];
    const float* proj_b = (const float*)d_in[12];
    const float* final_w= (const float*)d_in[13];
    const float* final_b= (const float*)d_in[14];
    float* ws  = (float*)d_ws;
    float* out = (float*)d_out;

    // weight prep
    prep_kernel<<<3246, 256, 0, stream>>>(pw1_w, pw2_w, pw3_w, pw4_w, head_w,
                                          proj_w, proj_b, final_w, final_b, ws);

    // TV Chambolle: 20 iterations in 2 register-resident launches (10+10),
    // 512-thread blocks (8 waves) for latency hiding.
    dim3 tvg(12, 16, 4);                           // 44-col x 32-row output tiles (768 blocks)
    tv_reg<10, true,  false><<<tvg, 512, 0, stream>>>(img, img,       ws + O_PA);  // 1-10
    tv_reg<10, false, true ><<<tvg, 512, 0, stream>>>(img, ws + O_PA, ws + O_DEN); // 11-20 -> den

    // fused stem + dw1 + pw1 (den -> [B][64][128][128])
    stem_dw1_pw1<<<dim3(16, 16, 4), 256, 0, stream>>>(ws + O_DEN, stem_w, dw1_w,
                                                      ws + O_WT1, ws + O_A1);

    // backbone
    dw_kernel<64, 128><<<4096, 256, 0, stream>>>(ws + O_A1, dw2_w, ws + O_A2);
    pw_gemm<64, 1, 2, 128, false><<<dim3(64, 2, 8), 256, 0, stream>>>(ws + O_A2, ws + O_WT2, ws + O_PA, 4096);

    dw_reduce2_kernel<128, 64><<<2048, 256, 0, stream>>>(ws + O_PA, dw3_w, ws + O_A1);
    pw_gemm<128, 1, 2, 256, false><<<dim3(16, 4, 8), 256, 0, stream>>>(ws + O_A1, ws + O_WT3, ws + O_PA, 1024);

    dw_reduce2_kernel<256, 32><<<1024, 256, 0, stream>>>(ws + O_PA, dw4_w, ws + O_A2);
    pw_gemm<256, 1, 4, 512, false><<<dim3(4, 8, 16), 256, 0, stream>>>(ws + O_A2, ws + O_WT4, ws + O_PA, 256);

    // head 512->1280 @16x16: fused 4-way partial reduce+SiLU at staging, split-4 raw out -> A1
    pw_gemm<512, 4, 4, 1280, false><<<dim3(4, 20, 16), 256, 0, stream>>>(ws + O_PA, ws + O_WTH, ws + O_A1, 256);
    tail_head<<<64, 256, 0, stream>>>(ws + O_A1, ws + O_WCOMB, ws + O_BCOMB, ws + O_S);

    resize_haar<<<256, 256, 0, stream>>>(ws + O_S, final_b, out);
}